// Round 1
// 264.824 us; speedup vs baseline: 1.1089x; 1.1089x over previous
//
#include <hip/hip_runtime.h>
#include <math.h>

// Problem constants
#define NTOK 8192
#define MDIM 4096
#define NEXP 64
#define CAPACITY 128.0f

// Output layout (all fp32): [indices 8192][capacity 1][locations 8192][gates 8192][num_experts 1]
#define OFF_IDX  0
#define OFF_CAP  8192
#define OFF_LOC  8193
#define OFF_GATE 16385
#define OFF_NE   24577

// GEMM decomposition
#define NSLICE 4
#define KSLICE (MDIM / NSLICE)     // 1024 K per slice
#define KC     64                  // K-chunk staged per iteration
#define NCHUNK (KSLICE / KC)       // 16

// ws layout in 4-byte words: [cnt 8192][rk 8192][part NSLICE*8192*64][Wsplit 3*64*4096 bf16]
#define WS_CNT_OFF  0
#define WS_RK_OFF   8192
#define WS_PART_OFF 16384
#define WS_W_OFF    (WS_PART_OFF + NSLICE * NTOK * NEXP)

using bf16x8 = __attribute__((ext_vector_type(8))) short;
using f32x4  = __attribute__((ext_vector_type(4))) float;

// RNE float -> bf16 bits
static __device__ __forceinline__ unsigned short f2bf(float f) {
    union { float f; unsigned u; } v; v.f = f;
    unsigned r = v.u + 0x7fffu + ((v.u >> 16) & 1u);
    return (unsigned short)(r >> 16);
}
static __device__ __forceinline__ float bf2f(unsigned short h) {
    union { unsigned u; float f; } v; v.u = ((unsigned)h) << 16;
    return v.f;
}

// ---------------------------------------------------------------------------
// Pre-split W [64][4096] fp32 -> Ws[3][64][4096] bf16 (hi/mid/lo terms).
// 65536 threads, one float4 each. ~2.5 MB traffic, negligible.
// ---------------------------------------------------------------------------
__global__ __launch_bounds__(256) void prep_w(
    const float* __restrict__ W, unsigned short* __restrict__ Ws)
{
    const int gid = blockIdx.x * 256 + threadIdx.x;   // 0..65535
    const int e   = gid >> 10;                        // expert row
    const int f4  = gid & 1023;                       // float4 within row
    float4 v = ((const float4*)W)[e * 1024 + f4];
    float av[4] = {v.x, v.y, v.z, v.w};
    unsigned short h[3][4];
    #pragma unroll
    for (int j = 0; j < 4; ++j) {
        float a = av[j];
        unsigned short b1 = f2bf(a);  float r1 = a  - bf2f(b1);
        unsigned short b2 = f2bf(r1); float r2 = r1 - bf2f(b2);
        unsigned short b3 = f2bf(r2);
        h[0][j] = b1; h[1][j] = b2; h[2][j] = b3;
    }
    #pragma unroll
    for (int t = 0; t < 3; ++t)
        *(ushort4*)&Ws[((size_t)(t * 64 + e)) * MDIM + f4 * 4] =
            make_ushort4(h[t][0], h[t][1], h[t][2], h[t][3]);
}

// ---------------------------------------------------------------------------
// fp32-accurate gate GEMM on the matrix pipe via 3-term bf16 split:
//   x ~= x1+x2+x3, W ~= w1+w2+w3 (bf16 each);
//   logits = x1w1 + x1w2 + x2w1 + x2w2 + x1w3 + x3w1  (6 MFMA products,
//   all C-chained into one fp32 accumulator; residual ~2^-24 relative).
// Block = 4 waves x 16 tokens = 64 tokens; grid (128 token-groups, 4 K-slices)
// = 512 blocks = 2/CU (8 waves/CU). Per KC=64 chunk: reg-stage x (coalesced
// float4, loads issued BEFORE compute, convert+ds_write after = T14 split),
// 3 bf16 planes in padded LDS (rows 72 bf16 -> 16B-aligned, 2-way banks =
// free), A-frags = contiguous ds_read_b128, B-frags straight from the
// L1/L2-hot pre-split W (1.5 MB), 48 MFMAs with 4 independent nt-chains.
// HBM-bound: streams x once (134 MB) -> ~21 us floor.
// ---------------------------------------------------------------------------
__global__ __launch_bounds__(256, 2) void gate_mfma(
    const float* __restrict__ x,
    const unsigned short* __restrict__ Ws,
    float* __restrict__ part)
{
    __shared__ __align__(16) unsigned short xs[2][3][64][72];  // 54 KB

    const int tid  = threadIdx.x;
    const int lane = tid & 63;
    const int wv   = tid >> 6;                 // 0..3
    const int tok0 = blockIdx.x * 64;
    const int slice = blockIdx.y;
    const int k0   = slice * KSLICE;

    const float4* __restrict__ x4 = (const float4*)x;

    float4 xr[4];

    // Issue the chunk's 16 KB of x as 4 coalesced float4 loads per thread.
    auto load_regs = [&](int c) {
        #pragma unroll
        for (int q = 0; q < 4; ++q) {
            const int f  = q * 256 + tid;      // 0..1023
            const int tr = f >> 4;             // token 0..63
            const int k4 = f & 15;             // float4 within 64-K chunk
            xr[q] = x4[(size_t)(tok0 + tr) * (MDIM / 4) + (k0 >> 2) + c * 16 + k4];
        }
    };

    // Convert staged registers to 3 bf16 planes and write to LDS buffer b.
    auto cvt_write = [&](int b) {
        #pragma unroll
        for (int q = 0; q < 4; ++q) {
            const int f  = q * 256 + tid;
            const int tr = f >> 4;
            const int k4 = f & 15;
            float av[4] = {xr[q].x, xr[q].y, xr[q].z, xr[q].w};
            unsigned short h[3][4];
            #pragma unroll
            for (int j = 0; j < 4; ++j) {
                float a = av[j];
                unsigned short b1 = f2bf(a);  float r1 = a  - bf2f(b1);
                unsigned short b2 = f2bf(r1); float r2 = r1 - bf2f(b2);
                unsigned short b3 = f2bf(r2);
                h[0][j] = b1; h[1][j] = b2; h[2][j] = b3;
            }
            #pragma unroll
            for (int t = 0; t < 3; ++t)
                *(ushort4*)&xs[b][t][tr][k4 * 4] =
                    make_ushort4(h[t][0], h[t][1], h[t][2], h[t][3]);
        }
    };

    f32x4 acc[4];
    #pragma unroll
    for (int nt = 0; nt < 4; ++nt) acc[nt] = (f32x4){0.f, 0.f, 0.f, 0.f};

    // A-frag: row m = lane&15 (token), k = (lane>>4)*8 + j (contiguous 16 B).
    // B-frag: col n = lane&15 (expert), same k mapping -> contiguous 16 B of Ws[e][k].
    auto compute = [&](int b, int c) {
        const int m = lane & 15;
        const int g = lane >> 4;
        #pragma unroll
        for (int ks = 0; ks < 2; ++ks) {
            const int kk = ks * 32 + g * 8;
            bf16x8 a[3];
            #pragma unroll
            for (int t = 0; t < 3; ++t)
                a[t] = *(const bf16x8*)&xs[b][t][wv * 16 + m][kk];
            bf16x8 w[3][4];
            #pragma unroll
            for (int t = 0; t < 3; ++t)
                #pragma unroll
                for (int nt = 0; nt < 4; ++nt)
                    w[t][nt] = *(const bf16x8*)
                        &Ws[((size_t)(t * 64 + nt * 16 + m)) * MDIM + k0 + c * KC + kk];
            // 6 split-products, smallest first; nt-chains interleaved for ILP.
            #pragma unroll
            for (int nt = 0; nt < 4; ++nt)
                acc[nt] = __builtin_amdgcn_mfma_f32_16x16x32_bf16(a[2], w[0][nt], acc[nt], 0, 0, 0);
            #pragma unroll
            for (int nt = 0; nt < 4; ++nt)
                acc[nt] = __builtin_amdgcn_mfma_f32_16x16x32_bf16(a[0], w[2][nt], acc[nt], 0, 0, 0);
            #pragma unroll
            for (int nt = 0; nt < 4; ++nt)
                acc[nt] = __builtin_amdgcn_mfma_f32_16x16x32_bf16(a[1], w[1][nt], acc[nt], 0, 0, 0);
            #pragma unroll
            for (int nt = 0; nt < 4; ++nt)
                acc[nt] = __builtin_amdgcn_mfma_f32_16x16x32_bf16(a[1], w[0][nt], acc[nt], 0, 0, 0);
            #pragma unroll
            for (int nt = 0; nt < 4; ++nt)
                acc[nt] = __builtin_amdgcn_mfma_f32_16x16x32_bf16(a[0], w[1][nt], acc[nt], 0, 0, 0);
            #pragma unroll
            for (int nt = 0; nt < 4; ++nt)
                acc[nt] = __builtin_amdgcn_mfma_f32_16x16x32_bf16(a[0], w[0][nt], acc[nt], 0, 0, 0);
        }
    };

    load_regs(0);
    cvt_write(0);
    __syncthreads();

    for (int c = 0; c < NCHUNK; ++c) {
        const int cur = c & 1;
        if (c + 1 < NCHUNK) load_regs(c + 1);   // issue early: HBM under MFMA
        compute(cur, c);
        if (c + 1 < NCHUNK) cvt_write(cur ^ 1); // write late, other buffer
        __syncthreads();
    }

    // C/D layout (m89-verified): col = lane&15, row = (lane>>4)*4 + reg.
    #pragma unroll
    for (int nt = 0; nt < 4; ++nt)
        #pragma unroll
        for (int r = 0; r < 4; ++r) {
            const int tokr = tok0 + wv * 16 + (lane >> 4) * 4 + r;
            part[((size_t)slice * NTOK + tokr) * 64 + nt * 16 + (lane & 15)] = acc[nt][r];
        }
}

// ---------------------------------------------------------------------------
// Fused reduce + argmax/softmax + per-chunk histogram/rank. (unchanged)
// grid 128 blocks (one per 64-token chunk), block 256 = 4 waves.
// ---------------------------------------------------------------------------
template<int S>
__global__ __launch_bounds__(256) void reduce_count(
    const float* __restrict__ part,
    float* __restrict__ out,
    int* __restrict__ cnt,
    int* __restrict__ rk)
{
    __shared__ int eidx[64];

    const int tid  = threadIdx.x;
    const int lane = tid & 63;
    const int wv   = tid >> 6;
    const int tok0 = blockIdx.x * 64;
    const int trel = wv * 16 + (lane >> 2);
    const int tok  = tok0 + trel;
    const int q    = lane & 3;

    const float4* __restrict__ p4 = (const float4*)part;

    float4 a[4];
    #pragma unroll
    for (int r = 0; r < 4; ++r) a[r] = make_float4(0.f, 0.f, 0.f, 0.f);
    for (int s = 0; s < S; ++s) {
        #pragma unroll
        for (int r = 0; r < 4; ++r) {
            float4 v = p4[((size_t)s * NTOK + tok) * 16 + q * 4 + r];
            a[r].x += v.x; a[r].y += v.y; a[r].z += v.z; a[r].w += v.w;
        }
    }

    float vals[16];
    #pragma unroll
    for (int r = 0; r < 4; ++r) {
        vals[r * 4 + 0] = a[r].x; vals[r * 4 + 1] = a[r].y;
        vals[r * 4 + 2] = a[r].z; vals[r * 4 + 3] = a[r].w;
    }

    float bm = vals[0];
    int   be = q * 16;
    #pragma unroll
    for (int j = 1; j < 16; ++j)
        if (vals[j] > bm) { bm = vals[j]; be = q * 16 + j; }
    #pragma unroll
    for (int off = 1; off <= 2; off <<= 1) {
        float om = __shfl_xor(bm, off, 64);
        int   oe = __shfl_xor(be, off, 64);
        if (om > bm || (om == bm && oe < be)) { bm = om; be = oe; }
    }

    float es = 0.f;
    #pragma unroll
    for (int j = 0; j < 16; ++j) es += expf(vals[j] - bm);
    #pragma unroll
    for (int off = 1; off <= 2; off <<= 1)
        es += __shfl_xor(es, off, 64);

    if (q == 0) {
        out[OFF_IDX  + tok] = (float)be;
        out[OFF_GATE + tok] = 1.0f / es;
        eidx[trel] = be;
    }
    __syncthreads();

    if (tid < 64) {
        const int e = eidx[tid];
        const unsigned long long lt =
            (tid == 0) ? 0ull : ((~0ull) >> (64 - tid));
        unsigned long long mymask = 0;
        int myrk = 0;
        for (int ee = 0; ee < 64; ++ee) {
            unsigned long long mb = __ballot(e == ee);
            if (tid == ee) mymask = mb;
            if (e == ee)   myrk   = (int)__popcll(mb & lt);
        }
        cnt[blockIdx.x * 64 + tid] = (int)__popcll(mymask);
        rk[tok0 + tid] = myrk;
    }
    if (tid == 0 && blockIdx.x == 0) {
        out[OFF_CAP] = CAPACITY;
        out[OFF_NE]  = (float)NEXP;
    }
}

// ---------------------------------------------------------------------------
// Fused scan + final (unchanged): one block, 1024 threads.
// ---------------------------------------------------------------------------
__global__ __launch_bounds__(1024) void scan_final(
    const float* __restrict__ idxf,
    const int* __restrict__ cnt,
    const int* __restrict__ rk,
    float* __restrict__ out)
{
    __shared__ int lcnt[128 * 64];   // 32 KB
    __shared__ int wtot[16 * 64];    // 4 KB

    const int tid  = threadIdx.x;
    const int lane = tid & 63;
    const int w    = tid >> 6;       // 0..15

    #pragma unroll
    for (int j = 0; j < 8; ++j) lcnt[j * 1024 + tid] = cnt[j * 1024 + tid];
    __syncthreads();

    {
        int sum = 0;
        #pragma unroll
        for (int j = 0; j < 8; ++j) sum += lcnt[(w * 8 + j) * 64 + lane];
        wtot[w * 64 + lane] = sum;
    }
    __syncthreads();

    if (tid < 64) {
        int run = 0;
        #pragma unroll
        for (int w2 = 0; w2 < 16; ++w2) {
            int t = wtot[w2 * 64 + tid];
            wtot[w2 * 64 + tid] = run;
            run += t;
        }
    }
    __syncthreads();

    {
        int run = wtot[w * 64 + lane];
        #pragma unroll
        for (int j = 0; j < 8; ++j) {
            int c = w * 8 + j;
            int v = lcnt[c * 64 + lane];
            lcnt[c * 64 + lane] = run;
            run += v;
        }
    }
    __syncthreads();

    #pragma unroll
    for (int j = 0; j < 8; ++j) {
        int s = j * 1024 + tid;
        int e = (int)idxf[s];
        out[OFF_LOC + s] = (float)(lcnt[(s >> 6) * 64 + e] + rk[s]);
    }
}

extern "C" void kernel_launch(void* const* d_in, const int* in_sizes, int n_in,
                              void* d_out, int out_size, void* d_ws, size_t ws_size,
                              hipStream_t stream)
{
    const float* x = (const float*)d_in[0];   // [8192, 4096] fp32
    const float* W = (const float*)d_in[1];   // [64, 4096] fp32
    float* out = (float*)d_out;               // 24578 fp32

    int*   cnt  = (int*)d_ws + WS_CNT_OFF;
    int*   rk   = (int*)d_ws + WS_RK_OFF;
    float* part = (float*)d_ws + WS_PART_OFF;
    unsigned short* Ws = (unsigned short*)((int*)d_ws + WS_W_OFF);

    // total ws need: (16384 + 4*8192*64 + 3*64*4096/2) words ~ 9.6 MB
    // (prior session's S=8 branch used 16.8 MB, so this always fits)

    prep_w<<<256, 256, 0, stream>>>(W, Ws);
    gate_mfma<<<dim3(128, NSLICE), 256, 0, stream>>>(x, Ws, part);
    reduce_count<NSLICE><<<128, 256, 0, stream>>>(part, out, cnt, rk);
    scan_final<<<1, 1024, 0, stream>>>(out + OFF_IDX, cnt, rk, out);
}